// Round 7
// baseline (521.662 us; speedup 1.0000x reference)
//
#include <hip/hip_runtime.h>
#include <stdint.h>

// Sizes (fixed by the problem)
#define BATCH   65536
#define D_IN    784
#define KP      832      // D_IN padded to a multiple of BK=64
#define HDIM    512
#define D_OUT   10
#define NCODE   512
#define HT_LD   520      // epilogue LDS tile leading dim (512 + 8 f16 pad)

typedef _Float16 f16;
typedef _Float16 f16x8 __attribute__((ext_vector_type(8)));
typedef float    f32x4 __attribute__((ext_vector_type(4)));

__device__ __forceinline__ void gld_lds16(const void* g, void* l) {
  __builtin_amdgcn_global_load_lds((const __attribute__((address_space(1))) void*)g,
                                   (__attribute__((address_space(3))) void*)l, 16, 0, 0);
}

#define MEMFENCE asm volatile("" ::: "memory")
#define BARRIER() do { MEMFENCE; __builtin_amdgcn_s_barrier(); MEMFENCE; } while (0)
#define LGKM0 asm volatile("s_waitcnt lgkmcnt(0)" ::: "memory")

// ---------------- merged VQ: blocks [0,3584) -> W1 path, [3584,7680) -> W2 path ----
// Replicates numpy-fp32 semantics (verified: absmax 0.0156).
__global__ void k_vq(const float* __restrict__ W1, const float* __restrict__ E1,
                     f16* __restrict__ qW1,
                     const float* __restrict__ W2, const float* __restrict__ E2,
                     f16* __restrict__ qW2, float* __restrict__ diffacc) {
  #pragma clang fp contract(off)
  __shared__ float Es[28 * NCODE];
  __shared__ float Ts[NCODE];
  const int wid = threadIdx.x >> 6, lane = threadIdx.x & 63;
  if (blockIdx.x < 3584) {
    // ---- VQ W1: blocks (og<128, ig<112), dim 28 ----
    for (int i = threadIdx.x; i < 28 * NCODE; i += 256) Es[i] = E1[i];
    __syncthreads();
    for (int k = threadIdx.x; k < NCODE; k += 256) {
      float e0 = Es[k];
      float t = e0 * e0;
      for (int j = 1; j < 28; ++j) {
        float e = Es[j * NCODE + k];
        float ee = e * e;
        t = t + ee;
      }
      Ts[k] = t;
    }
    __syncthreads();
    const int bid = blockIdx.x * 4 + wid;          // < 14336
    const int og = bid / 112, ig = bid % 112;
    float v[28], vv[28];
    #pragma unroll
    for (int j = 0; j < 28; ++j) {
      int om = j & 3, im = j >> 2;
      v[j] = W1[(og * 4 + om) * D_IN + ig * 7 + im];
      vv[j] = v[j] * v[j];
    }
    float r[8];
    #pragma unroll
    for (int j = 0; j < 8; ++j) r[j] = vv[j];
    #pragma unroll
    for (int j = 0; j < 8; ++j) r[j] = r[j] + vv[8 + j];
    #pragma unroll
    for (int j = 0; j < 8; ++j) r[j] = r[j] + vv[16 + j];
    float s = ((r[0] + r[1]) + (r[2] + r[3])) + ((r[4] + r[5]) + (r[6] + r[7]));
    s = s + vv[24]; s = s + vv[25]; s = s + vv[26]; s = s + vv[27];

    float bestd = 1e30f; int bestk = 0x7fffffff;
    for (int t = 0; t < 8; ++t) {
      int k = t * 64 + lane;
      float dot = 0.f;
      #pragma unroll
      for (int j = 0; j < 28; ++j) dot = __builtin_fmaf(v[j], Es[j * NCODE + k], dot);
      float d = (s - 2.0f * dot) + Ts[k];
      if (d < bestd || (d == bestd && k < bestk)) { bestd = d; bestk = k; }
    }
    for (int off = 32; off; off >>= 1) {
      float d2 = __shfl_down(bestd, off, 64);
      int   k2 = __shfl_down(bestk, off, 64);
      if (d2 < bestd || (d2 == bestd && k2 < bestk)) { bestd = d2; bestk = k2; }
    }
    int kstar = __shfl(bestk, 0, 64);
    float sq = 0.f;
    if (lane < 28) {
      int om = lane & 3, im = lane >> 2;
      float q = Es[lane * NCODE + kstar];
      qW1[(size_t)(og * 4 + om) * KP + ig * 7 + im] = (f16)q;
      float dd = q - v[lane]; sq = dd * dd;
    }
    for (int off = 32; off; off >>= 1) sq += __shfl_down(sq, off, 64);
    if (lane == 0) atomicAdd(&diffacc[bid & 127], sq);
  } else {
    // ---- VQ W2: blocks (og<512, ig<32), dim 16 contiguous ----
    for (int i = threadIdx.x; i < 16 * NCODE; i += 256) Es[i] = E2[i];
    __syncthreads();
    for (int k = threadIdx.x; k < NCODE; k += 256) {
      float e0 = Es[k];
      float t = e0 * e0;
      for (int j = 1; j < 16; ++j) {
        float e = Es[j * NCODE + k];
        float ee = e * e;
        t = t + ee;
      }
      Ts[k] = t;
    }
    __syncthreads();
    const int bid = (blockIdx.x - 3584) * 4 + wid; // < 16384
    const int og = bid >> 5, ig = bid & 31;
    float v[16], vv[16];
    #pragma unroll
    for (int j = 0; j < 16; ++j) {
      v[j] = W2[og * HDIM + ig * 16 + j];
      vv[j] = v[j] * v[j];
    }
    float r[8];
    #pragma unroll
    for (int j = 0; j < 8; ++j) r[j] = vv[j];
    #pragma unroll
    for (int j = 0; j < 8; ++j) r[j] = r[j] + vv[8 + j];
    float s = ((r[0] + r[1]) + (r[2] + r[3])) + ((r[4] + r[5]) + (r[6] + r[7]));

    float bestd = 1e30f; int bestk = 0x7fffffff;
    for (int t = 0; t < 8; ++t) {
      int k = t * 64 + lane;
      float dot = 0.f;
      #pragma unroll
      for (int j = 0; j < 16; ++j) dot = __builtin_fmaf(v[j], Es[j * NCODE + k], dot);
      float d = (s - 2.0f * dot) + Ts[k];
      if (d < bestd || (d == bestd && k < bestk)) { bestd = d; bestk = k; }
    }
    for (int off = 32; off; off >>= 1) {
      float d2 = __shfl_down(bestd, off, 64);
      int   k2 = __shfl_down(bestk, off, 64);
      if (d2 < bestd || (d2 == bestd && k2 < bestk)) { bestd = d2; bestk = k2; }
    }
    int kstar = __shfl(bestk, 0, 64);
    float sq = 0.f;
    if (lane < 16) {
      float q = Es[lane * NCODE + kstar];
      qW2[(size_t)og * HDIM + ig * 16 + lane] = (f16)q;
      float dd = q - v[lane]; sq = dd * dd;
    }
    for (int off = 32; off; off >>= 1) sq += __shfl_down(sq, off, 64);
    if (lane == 0) atomicAdd(&diffacc[128 + (bid & 127)], sq);
  }
}

// ---------------- GEMM1: h = relu(x @ qW1^T + b1), fused cvt + column stats ----------
// Multi-phase schedule (T3/T4/T5): each BK=64 tile split into 4 phases, each
// {ds-read subtile || issue stage ops -> barrier -> lgkmcnt(0) -> setprio+16 MFMA
//  -> barrier}. B double-buffered (2x64KB), DMA front-loaded ph0/ph1 (>=2 phases
// to land); A single-buffered [128][64]: reads confined to ph0 (af for both ks
// held in regs), rewrite for tile k+1 in ph2 (barrier-separated). vmcnt(0) only
// at ph3 -- by then everything in flight is >=2 phases old (counted by
// construction, no young loads drained). MFMA per-acc order unchanged (ks
// ascending) -> bitwise-identical h.
__global__ void __launch_bounds__(512, 2)
k_gemm1(const float* __restrict__ X, const f16* __restrict__ Bw,
        const float* __restrict__ bias, f16* __restrict__ C,
        float* __restrict__ statacc) {
  __shared__ __align__(16) char lds_all[147456];  // A[0,16K) B0[16K,80K) B1[80K,144K); epi: ht 130K + cls
  f16* ht = (f16*)lds_all;
  float* cls  = (float*)(lds_all + 137216);       // epilogue-only (aliases dead B1 tail)
  float* cls2 = (float*)(lds_all + 139264);
  const int tid = threadIdx.x;
  const int bm = blockIdx.x;                      // 512 blocks, rows owned exclusively
  const int lane = tid & 63, wid = tid >> 6;
  const int waveM = wid & 1, waveN = wid >> 1;    // 2M x 4N waves
  const int l15 = lane & 15, quad = lane >> 4;

  // A staging: thread owns row rA = tid>>2, chunks {cA, cA+4} of the 128x64 tile.
  const int rA = tid >> 2, cA = tid & 3;
  const float* gArow = X + (size_t)(bm * 128 + rA) * D_IN;
  const int wA0 = rA * 64 + ((cA ^ (rA & 7)) * 8);          // swizzled chunk slots
  const int wA1 = rA * 64 + (((cA + 4) ^ (rA & 7)) * 8);
  // B staging: 8 slots/thread of the 512x64 tile; linear LDS dest, source
  // chunk pre-swizzled (both-sides swizzle, G21).
  const f16* gBp[8]; int lBoff[8];
  #pragma unroll
  for (int i = 0; i < 8; ++i) {
    int s = tid + i * 512;
    int rB = s >> 3, cB = s & 7;
    gBp[i] = Bw + (size_t)rB * KP + ((cB ^ (rB & 7)) * 8);
    lBoff[i] = s * 8;
  }

  f32x4 acc[4][8];
  #pragma unroll
  for (int i = 0; i < 4; ++i)
    #pragma unroll
    for (int j = 0; j < 8; ++j) acc[i][j] = (f32x4){0.f, 0.f, 0.f, 0.f};

  const int swz = (l15 & 7);
  const int arow = waveM * 64 + l15;
  const int brow = waveN * 128 + l15;

  float4 ra0, ra1, ra2, ra3;
  auto issueA = [&](int k0) {
    int g0 = k0 + cA * 8;
    int g1 = k0 + (cA + 4) * 8;
    int g0c = g0 < D_IN ? g0 : 0;   // clamp: always issue (vmcnt determinism)
    int g1c = g1 < D_IN ? g1 : 0;
    ra0 = *(const float4*)(gArow + g0c);
    ra1 = *(const float4*)(gArow + g0c + 4);
    ra2 = *(const float4*)(gArow + g1c);
    ra3 = *(const float4*)(gArow + g1c + 4);
  };
  auto writeA = [&](int k0) {
    float4 a0 = ra0, a1 = ra1, b0 = ra2, b1 = ra3;
    if (k0 + cA * 8 >= D_IN)       { a0 = (float4){0.f,0.f,0.f,0.f}; a1 = a0; }
    if (k0 + (cA + 4) * 8 >= D_IN) { b0 = (float4){0.f,0.f,0.f,0.f}; b1 = b0; }
    f16x8 o0, o1;
    o0[0]=(f16)a0.x; o0[1]=(f16)a0.y; o0[2]=(f16)a0.z; o0[3]=(f16)a0.w;
    o0[4]=(f16)a1.x; o0[5]=(f16)a1.y; o0[6]=(f16)a1.z; o0[7]=(f16)a1.w;
    o1[0]=(f16)b0.x; o1[1]=(f16)b0.y; o1[2]=(f16)b0.z; o1[3]=(f16)b0.w;
    o1[4]=(f16)b1.x; o1[5]=(f16)b1.y; o1[6]=(f16)b1.z; o1[7]=(f16)b1.w;
    *(f16x8*)((f16*)lds_all + wA0) = o0;
    *(f16x8*)((f16*)lds_all + wA1) = o1;
  };
  auto issueB4 = [&](int k0, int bOff, int half) {
    f16* Bs_ = (f16*)(lds_all + bOff);
    #pragma unroll
    for (int i = 0; i < 4; ++i) gld_lds16(gBp[half * 4 + i] + k0, Bs_ + lBoff[half * 4 + i]);
  };
  auto rdA = [&](int ks, f16x8 (&af)[4]) {
    const f16* As_ = (const f16*)lds_all;
    const int coff = ((ks * 4 + quad) ^ swz) * 8;
    #pragma unroll
    for (int i = 0; i < 4; ++i) af[i] = *(const f16x8*)(As_ + (arow + i * 16) * 64 + coff);
  };
  auto rdB = [&](int bOff, int ks, int j0, f16x8 (&bf)[4]) {
    const f16* Bs_ = (const f16*)(lds_all + bOff);
    const int coff = ((ks * 4 + quad) ^ swz) * 8;
    #pragma unroll
    for (int j = 0; j < 4; ++j) bf[j] = *(const f16x8*)(Bs_ + (brow + (j0 + j) * 16) * 64 + coff);
  };
  auto mm16 = [&](const f16x8 (&af)[4], const f16x8 (&bf)[4], int j0) {
    #pragma unroll
    for (int i = 0; i < 4; ++i)
      #pragma unroll
      for (int j = 0; j < 4; ++j)
        acc[i][j0 + j] = __builtin_amdgcn_mfma_f32_16x16x32_f16(af[i], bf[j], acc[i][j0 + j], 0, 0, 0);
  };

  const int NT = KP / 64;                   // 13
  // prologue: A(0) regs->LDS, B(0) DMA, drain, go.
  issueA(0); MEMFENCE;
  issueB4(0, 16384, 0); issueB4(0, 16384, 1); MEMFENCE;
  writeA(0); MEMFENCE;
  asm volatile("s_waitcnt vmcnt(0) lgkmcnt(0)" ::: "memory");
  BARRIER();

  for (int k = 0; k < NT; ++k) {
    const int bOff = 16384 + (k & 1) * 65536;
    const int nOff = 16384 + ((k + 1) & 1) * 65536;
    const bool more = (k + 1 < NT);
    f16x8 af0[4], af1[4], bf[4];
    // ---- phase 0: all A-frags + B(ks0,j0-3); issue gA(k+1) + B(k+1) half0 ----
    rdA(0, af0); rdA(1, af1); rdB(bOff, 0, 0, bf);
    if (more) { issueA((k + 1) * 64); MEMFENCE; issueB4((k + 1) * 64, nOff, 0); }
    BARRIER(); LGKM0;
    __builtin_amdgcn_s_setprio(1); mm16(af0, bf, 0); __builtin_amdgcn_s_setprio(0);
    BARRIER();
    // ---- phase 1: B(ks0,j4-7); issue B(k+1) half1 ----
    rdB(bOff, 0, 4, bf);
    if (more) issueB4((k + 1) * 64, nOff, 1);
    BARRIER(); LGKM0;
    __builtin_amdgcn_s_setprio(1); mm16(af0, bf, 4); __builtin_amdgcn_s_setprio(0);
    BARRIER();
    // ---- phase 2: B(ks1,j0-3); writeA(k+1) (A reads done by ph0-barrier) ----
    rdB(bOff, 1, 0, bf);
    if (more) writeA((k + 1) * 64);         // implicit vmcnt retires gA(k+1)
    BARRIER(); LGKM0;
    __builtin_amdgcn_s_setprio(1); mm16(af1, bf, 0); __builtin_amdgcn_s_setprio(0);
    BARRIER();
    // ---- phase 3: B(ks1,j4-7); tile-boundary vmcnt (B(k+1) is >=2 phases old) ----
    rdB(bOff, 1, 4, bf);
    MEMFENCE;
    if (more) asm volatile("s_waitcnt vmcnt(0)" ::: "memory");
    BARRIER(); LGKM0;
    __builtin_amdgcn_s_setprio(1); mm16(af1, bf, 4); __builtin_amdgcn_s_setprio(0);
    BARRIER();
  }
  __syncthreads();                          // staging dead; reuse LDS as ht/cls

  // epilogue: relu+bias -> ht (f16) + per-column stats on fp32 values
  cls[tid] = 0.f; cls2[tid] = 0.f;
  __syncthreads();
  const int colbase = waveN * 128 + l15;
  float bcol[8];
  #pragma unroll
  for (int j = 0; j < 8; ++j) bcol[j] = bias[colbase + j * 16];
  float cs[8], cs2[8];
  #pragma unroll
  for (int j = 0; j < 8; ++j) { cs[j] = 0.f; cs2[j] = 0.f; }
  #pragma unroll
  for (int i = 0; i < 4; ++i)
    #pragma unroll
    for (int r2 = 0; r2 < 4; ++r2) {
      int rloc = waveM * 64 + i * 16 + quad * 4 + r2;
      #pragma unroll
      for (int j = 0; j < 8; ++j) {
        float v = acc[i][j][r2] + bcol[j];
        v = v > 0.f ? v : 0.f;
        ht[rloc * HT_LD + waveN * 128 + j * 16 + l15] = (f16)v;
        cs[j] += v; cs2[j] += v * v;
      }
    }
  #pragma unroll
  for (int j = 0; j < 8; ++j) {
    cs[j]  += __shfl_xor(cs[j], 16, 64);  cs[j]  += __shfl_xor(cs[j], 32, 64);
    cs2[j] += __shfl_xor(cs2[j], 16, 64); cs2[j] += __shfl_xor(cs2[j], 32, 64);
  }
  if (quad == 0) {
    #pragma unroll
    for (int j = 0; j < 8; ++j) {
      atomicAdd(&cls[waveN * 128 + j * 16 + l15], cs[j]);
      atomicAdd(&cls2[waveN * 128 + j * 16 + l15], cs2[j]);
    }
  }
  __syncthreads();
  atomicAdd(&statacc[256 + tid], cls[tid]);
  atomicAdd(&statacc[768 + tid], cls2[tid]);
  // coalesced h write-back: wave w -> rows w*16..w*16+15; one 1KB row per store
  #pragma unroll
  for (int rr = 0; rr < 16; ++rr) {
    int row = wid * 16 + rr;
    f16x8 vrow = *(const f16x8*)(ht + row * HT_LD + lane * 8);
    *(f16x8*)(C + (size_t)(bm * 128 + row) * HDIM + lane * 8) = vrow;
  }
}

// ---------------- BN coefs + fold into qW2 + bias2 + W3 prep (merged) ----------------
// Every block recomputes ab from accum (deterministic, identical); block 0 also
// writes W3h (10->16 row pad) and the diff output.
__global__ void k_bnfold(const float* __restrict__ acc, const float* __restrict__ gamma,
                         const float* __restrict__ beta, const float* __restrict__ b2,
                         f16* __restrict__ qW2, float* __restrict__ bias2,
                         const float* __restrict__ W3, f16* __restrict__ W3h,
                         float* __restrict__ diff_out) {
  __shared__ float ab_a[512], ab_b[512], red[256];
  const int t = threadIdx.x, n = blockIdx.x;        // 512 blocks x 256 threads
  const float inv = 1.f / 65536.f;
  for (int c = t; c < 512; c += 256) {
    float mu = acc[256 + c] * inv;
    float msq = acc[768 + c] * inv;
    float var = msq - mu * mu;
    float a = gamma[c] / sqrtf(var + 1e-5f);
    ab_a[c] = a;
    ab_b[c] = beta[c] - mu * a;
  }
  __syncthreads();
  float partial = 0.f;
  #pragma unroll
  for (int kk = 0; kk < 2; ++kk) {
    int k = t + kk * 256;
    float w = (float)qW2[n * HDIM + k];
    partial += ab_b[k] * w;
    qW2[n * HDIM + k] = (f16)(ab_a[k] * w);
  }
  red[t] = partial; __syncthreads();
  for (int s = 128; s > 0; s >>= 1) { if (t < s) red[t] += red[t + s]; __syncthreads(); }
  if (t == 0) bias2[n] = b2[n] + red[0];
  if (n == 0) {
    for (int c = t; c < 512; c += 256) {
      #pragma unroll
      for (int o = 0; o < 16; ++o)
        W3h[o * HDIM + c] = (o < D_OUT) ? (f16)W3[o * HDIM + c] : (f16)0.f;
    }
    if (t == 0) {
      float s1 = 0.f, s2 = 0.f;
      for (int i = 0; i < 128; ++i) { s1 += acc[i]; s2 += acc[128 + i]; }
      diff_out[0] = s1 * (1.f / 401408.f) + s2 * (1.f / 262144.f);
    }
  }
}

// ---------------- GEMM2 + fused final layer (same 4-phase schedule) ----------------
__global__ void __launch_bounds__(512, 2)
k_gemm2f(const f16* __restrict__ A, const f16* __restrict__ Bw,
         const float* __restrict__ bias2, const f16* __restrict__ W3h,
         const float* __restrict__ b3, float* __restrict__ out) {
  __shared__ __align__(16) char lds_all[147456];
  f16* ht = (f16*)lds_all;
  const int tid = threadIdx.x;
  const int bm = blockIdx.x;
  const int lane = tid & 63, wid = tid >> 6;
  const int waveM = wid & 1, waveN = wid >> 1;
  const int l15 = lane & 15, quad = lane >> 4;

  const int rA = tid >> 2, cA = tid & 3;
  const f16* gArow = A + (size_t)(bm * 128 + rA) * HDIM;
  const int wA0 = rA * 64 + ((cA ^ (rA & 7)) * 8);
  const int wA1 = rA * 64 + (((cA + 4) ^ (rA & 7)) * 8);
  const f16* gBp[8]; int lBoff[8];
  #pragma unroll
  for (int i = 0; i < 8; ++i) {
    int s = tid + i * 512;
    int rB = s >> 3, cB = s & 7;
    gBp[i] = Bw + (size_t)rB * HDIM + ((cB ^ (rB & 7)) * 8);
    lBoff[i] = s * 8;
  }

  f32x4 acc[4][8];
  #pragma unroll
  for (int i = 0; i < 4; ++i)
    #pragma unroll
    for (int j = 0; j < 8; ++j) acc[i][j] = (f32x4){0.f, 0.f, 0.f, 0.f};

  const int swz = (l15 & 7);
  const int arow = waveM * 64 + l15;
  const int brow = waveN * 128 + l15;

  f16x8 ra0, ra1;
  auto issueA = [&](int k0) {
    ra0 = *(const f16x8*)(gArow + k0 + cA * 8);
    ra1 = *(const f16x8*)(gArow + k0 + (cA + 4) * 8);
  };
  auto writeA = [&]() {
    *(f16x8*)((f16*)lds_all + wA0) = ra0;
    *(f16x8*)((f16*)lds_all + wA1) = ra1;
  };
  auto issueB4 = [&](int k0, int bOff, int half) {
    f16* Bs_ = (f16*)(lds_all + bOff);
    #pragma unroll
    for (int i = 0; i < 4; ++i) gld_lds16(gBp[half * 4 + i] + k0, Bs_ + lBoff[half * 4 + i]);
  };
  auto rdA = [&](int ks, f16x8 (&af)[4]) {
    const f16* As_ = (const f16*)lds_all;
    const int coff = ((ks * 4 + quad) ^ swz) * 8;
    #pragma unroll
    for (int i = 0; i < 4; ++i) af[i] = *(const f16x8*)(As_ + (arow + i * 16) * 64 + coff);
  };
  auto rdB = [&](int bOff, int ks, int j0, f16x8 (&bf)[4]) {
    const f16* Bs_ = (const f16*)(lds_all + bOff);
    const int coff = ((ks * 4 + quad) ^ swz) * 8;
    #pragma unroll
    for (int j = 0; j < 4; ++j) bf[j] = *(const f16x8*)(Bs_ + (brow + (j0 + j) * 16) * 64 + coff);
  };
  auto mm16 = [&](const f16x8 (&af)[4], const f16x8 (&bf)[4], int j0) {
    #pragma unroll
    for (int i = 0; i < 4; ++i)
      #pragma unroll
      for (int j = 0; j < 4; ++j)
        acc[i][j0 + j] = __builtin_amdgcn_mfma_f32_16x16x32_f16(af[i], bf[j], acc[i][j0 + j], 0, 0, 0);
  };

  const int NT = HDIM / 64;                 // 8
  issueA(0); MEMFENCE;
  issueB4(0, 16384, 0); issueB4(0, 16384, 1); MEMFENCE;
  writeA(); MEMFENCE;
  asm volatile("s_waitcnt vmcnt(0) lgkmcnt(0)" ::: "memory");
  BARRIER();

  for (int k = 0; k < NT; ++k) {
    const int bOff = 16384 + (k & 1) * 65536;
    const int nOff = 16384 + ((k + 1) & 1) * 65536;
    const bool more = (k + 1 < NT);
    f16x8 af0[4], af1[4], bf[4];
    // phase 0
    rdA(0, af0); rdA(1, af1); rdB(bOff, 0, 0, bf);
    if (more) { issueA((k + 1) * 64); MEMFENCE; issueB4((k + 1) * 64, nOff, 0); }
    BARRIER(); LGKM0;
    __builtin_amdgcn_s_setprio(1); mm16(af0, bf, 0); __builtin_amdgcn_s_setprio(0);
    BARRIER();
    // phase 1
    rdB(bOff, 0, 4, bf);
    if (more) issueB4((k + 1) * 64, nOff, 1);
    BARRIER(); LGKM0;
    __builtin_amdgcn_s_setprio(1); mm16(af0, bf, 4); __builtin_amdgcn_s_setprio(0);
    BARRIER();
    // phase 2
    rdB(bOff, 1, 0, bf);
    if (more) writeA();                     // implicit vmcnt retires gA(k+1)
    BARRIER(); LGKM0;
    __builtin_amdgcn_s_setprio(1); mm16(af1, bf, 0); __builtin_amdgcn_s_setprio(0);
    BARRIER();
    // phase 3
    rdB(bOff, 1, 4, bf);
    MEMFENCE;
    if (more) asm volatile("s_waitcnt vmcnt(0)" ::: "memory");
    BARRIER(); LGKM0;
    __builtin_amdgcn_s_setprio(1); mm16(af1, bf, 4); __builtin_amdgcn_s_setprio(0);
    BARRIER();
  }
  __syncthreads();

  // epilogue: relu+bias2 -> ht (f16)
  const int colbase = waveN * 128 + l15;
  float bcol[8];
  #pragma unroll
  for (int j = 0; j < 8; ++j) bcol[j] = bias2[colbase + j * 16];
  #pragma unroll
  for (int i = 0; i < 4; ++i)
    #pragma unroll
    for (int r2 = 0; r2 < 4; ++r2) {
      int rloc = waveM * 64 + i * 16 + quad * 4 + r2;
      #pragma unroll
      for (int j = 0; j < 8; ++j) {
        float v = acc[i][j][r2] + bcol[j];
        v = v > 0.f ? v : 0.f;
        ht[rloc * HT_LD + waveN * 128 + j * 16 + l15] = (f16)v;
      }
    }
  __syncthreads();
  // final layer: wave w -> rows w*16..w*16+15; full K=512 in-block; direct store.
  f32x4 oacc = (f32x4){0.f, 0.f, 0.f, 0.f};
  #pragma unroll
  for (int ks = 0; ks < 16; ++ks) {
    f16x8 bfr = *(const f16x8*)(W3h + l15 * HDIM + ks * 32 + quad * 8);
    f16x8 afr = *(const f16x8*)(ht + (wid * 16 + l15) * HT_LD + ks * 32 + quad * 8);
    oacc = __builtin_amdgcn_mfma_f32_16x16x32_f16(afr, bfr, oacc, 0, 0, 0);
  }
  if (l15 < D_OUT) {
    float badd = b3[l15];
    #pragma unroll
    for (int r2 = 0; r2 < 4; ++r2) {
      int row = bm * 128 + wid * 16 + quad * 4 + r2;
      out[(size_t)row * D_OUT + l15] = oacc[r2] + badd;
    }
  }
}

extern "C" void kernel_launch(void* const* d_in, const int* in_sizes, int n_in,
                              void* d_out, int out_size, void* d_ws, size_t ws_size,
                              hipStream_t stream) {
  const float* x     = (const float*)d_in[0];
  const float* W1    = (const float*)d_in[1];
  const float* b1    = (const float*)d_in[2];
  const float* gamma = (const float*)d_in[3];
  const float* beta  = (const float*)d_in[4];
  const float* E1    = (const float*)d_in[5];
  const float* W2    = (const float*)d_in[6];
  const float* b2    = (const float*)d_in[7];
  const float* E2    = (const float*)d_in[8];
  const float* W3    = (const float*)d_in[9];
  const float* b3    = (const float*)d_in[10];
  float* out = (float*)d_out;

  char* ws = (char*)d_ws;
  float* accum = (float*)ws;                       // [0,128) diff1, [128,256) diff2, [256,768) colsum, [768,1280) colsumsq
  f16* qW1h = (f16*)(ws + 8192);                   // 512*832*2 = 851968
  f16* qW2h = (f16*)(ws + 860160);                 // 512*512*2 = 524288
  f16* W3h  = (f16*)(ws + 1384448);                // 16*512*2  = 16384
  float* bias2 = (float*)(ws + 1404928);           // 512*4
  f16* h    = (f16*)(ws + 1409024);                // 65536*512*2 = 67108864

  (void)hipMemsetAsync(ws, 0, 860160, stream);     // accum + qW1h (zero K-padding)
  k_vq<<<7680, 256, 0, stream>>>(W1, E1, qW1h, W2, E2, qW2h, accum);
  k_gemm1<<<512, 512, 0, stream>>>(x, qW1h, b1, h, accum);
  k_bnfold<<<512, 256, 0, stream>>>(accum, gamma, beta, b2, qW2h, bias2, W3, W3h,
                                    out + (size_t)BATCH * D_OUT);
  k_gemm2f<<<512, 512, 0, stream>>>(h, qW2h, bias2, W3h, b3, out);
}